// Round 1
// baseline (274.722 us; speedup 1.0000x reference)
//
#include <hip/hip_runtime.h>
#include <math.h>

// Problem constants (match reference: D=256, HID=512, N=100000)
#define DDIM   256
#define HID    512
#define SBLK   512   // number of stm partial blocks (also ltm)

// Workspace layout (float offsets)
#define OFF_M     0
#define OFF_L     (SBLK)
#define OFF_SACC  (2*SBLK)
#define OFF_LACC  (OFF_SACC + SBLK*DDIM)
#define OFF_FUSED (OFF_LACC + SBLK*DDIM)
#define OFF_H     (OFF_FUSED + 3*DDIM)
// total floats = 2*512 + 2*512*256 + 768 + 512 = 264448  (~1.01 MB)

// ---------------------------------------------------------------------------
// Kernel A: the heavy pass. blocks [0,512): stm online-softmax partials.
//           blocks [512,1024): ltm weighted-sum partials.
// Each wave splits D=256 across 64 lanes (float4 per lane, coalesced 1KB/row).
// ---------------------------------------------------------------------------
__global__ __launch_bounds__(256) void kA(const float* __restrict__ x_t,
                                          const float* __restrict__ stm_emb,
                                          const float* __restrict__ stm_w,
                                          const float* __restrict__ ltm_emb,
                                          const float* __restrict__ ltm_w,
                                          float* __restrict__ ws, int N)
{
    const int t    = threadIdx.x;
    const int lane = t & 63;
    const int wave = t >> 6;

    __shared__ float s_acc[4][DDIM];
    __shared__ float s_m[4];
    __shared__ float s_l[4];

    const float4 x4 = reinterpret_cast<const float4*>(x_t)[lane];

    const int bid = blockIdx.x;
    if (bid < SBLK) {
        // ---- STM: online softmax + weighted-sum fused, one pass ----
        const int b  = bid;
        const int rs = (int)(((long long)b     * N) / SBLK);
        const int re = (int)(((long long)(b+1) * N) / SBLK);
        const float4* emb4 = reinterpret_cast<const float4*>(stm_emb);

        float m = -INFINITY, l = 0.f;
        float ax = 0.f, ay = 0.f, az = 0.f, aw = 0.f;

        for (int r = rs + wave; r < re; r += 4) {
            float4 e = emb4[(size_t)r * 64 + lane];
            float  wv = stm_w[r];
            float  p  = e.x * x4.x + e.y * x4.y + e.z * x4.z + e.w * x4.w;
            #pragma unroll
            for (int off = 32; off > 0; off >>= 1)
                p += __shfl_xor(p, off, 64);      // bit-identical across lanes
            float s = p * wv;                     // wave-uniform
            float pe;
            if (s > m) {                          // wave-uniform branch
                float sc = __expf(m - s);         // exp(-inf)=0 on first row
                l *= sc; ax *= sc; ay *= sc; az *= sc; aw *= sc;
                m = s; pe = 1.f;
            } else {
                pe = __expf(s - m);
            }
            l  += pe;
            ax += pe * e.x; ay += pe * e.y; az += pe * e.z; aw += pe * e.w;
        }

        s_acc[wave][lane*4+0] = ax;
        s_acc[wave][lane*4+1] = ay;
        s_acc[wave][lane*4+2] = az;
        s_acc[wave][lane*4+3] = aw;
        if (lane == 0) { s_m[wave] = m; s_l[wave] = l; }
        __syncthreads();

        // block-level softmax merge (every wave has >=48 rows, all m finite)
        float M  = fmaxf(fmaxf(s_m[0], s_m[1]), fmaxf(s_m[2], s_m[3]));
        float e0 = __expf(s_m[0] - M), e1 = __expf(s_m[1] - M);
        float e2 = __expf(s_m[2] - M), e3 = __expf(s_m[3] - M);
        float L  = s_l[0]*e0 + s_l[1]*e1 + s_l[2]*e2 + s_l[3]*e3;
        float av = s_acc[0][t]*e0 + s_acc[1][t]*e1 + s_acc[2][t]*e2 + s_acc[3][t]*e3;
        ws[OFF_SACC + b*DDIM + t] = av;
        if (t == 0) { ws[OFF_M + b] = M; ws[OFF_L + b] = L; }
    } else {
        // ---- LTM: plain weighted sum ----
        const int b  = bid - SBLK;
        const int rs = (int)(((long long)b     * N) / SBLK);
        const int re = (int)(((long long)(b+1) * N) / SBLK);
        const float4* emb4 = reinterpret_cast<const float4*>(ltm_emb);

        float ax = 0.f, ay = 0.f, az = 0.f, aw = 0.f;
        for (int r = rs + wave; r < re; r += 4) {
            float4 e = emb4[(size_t)r * 64 + lane];
            float  wv = ltm_w[r];
            ax += wv * e.x; ay += wv * e.y; az += wv * e.z; aw += wv * e.w;
        }
        s_acc[wave][lane*4+0] = ax;
        s_acc[wave][lane*4+1] = ay;
        s_acc[wave][lane*4+2] = az;
        s_acc[wave][lane*4+3] = aw;
        __syncthreads();
        float av = s_acc[0][t] + s_acc[1][t] + s_acc[2][t] + s_acc[3][t];
        ws[OFF_LACC + b*DDIM + t] = av;
    }
}

// ---------------------------------------------------------------------------
// Kernel B: merge the 512 softmax partials + 512 ltm partials -> fused[768].
// grid=8 blocks; each block redundantly computes global (M,L), then owns 32
// d-columns. Block 0 also copies x_t into fused, inits h=b1 and out=b2.
// ---------------------------------------------------------------------------
__global__ __launch_bounds__(256) void kB(const float* __restrict__ x_t,
                                          const float* __restrict__ b1,
                                          const float* __restrict__ b2,
                                          float* __restrict__ ws,
                                          float* __restrict__ out)
{
    __shared__ float red[256];
    __shared__ float r1[256];
    __shared__ float r2[256];
    const int t = threadIdx.x;

    const float* ws_m = ws + OFF_M;
    const float* ws_l = ws + OFF_L;
    const float* sacc = ws + OFF_SACC;
    const float* lacc = ws + OFF_LACC;
    float* fused = ws + OFF_FUSED;
    float* hbuf  = ws + OFF_H;

    // global max M over 512 block maxima
    float mloc = fmaxf(ws_m[t], ws_m[t + 256]);
    red[t] = mloc; __syncthreads();
    for (int s = 128; s > 0; s >>= 1) {
        if (t < s) red[t] = fmaxf(red[t], red[t + s]);
        __syncthreads();
    }
    const float M = red[0];
    __syncthreads();

    // global denominator L
    float lloc = ws_l[t] * __expf(ws_m[t] - M) + ws_l[t + 256] * __expf(ws_m[t + 256] - M);
    red[t] = lloc; __syncthreads();
    for (int s = 128; s > 0; s >>= 1) {
        if (t < s) red[t] += red[t + s];
        __syncthreads();
    }
    const float L = red[0];
    __syncthreads();

    // this block owns d in [d0, d0+32)
    const int ell = t & 31;
    const int g   = t >> 5;          // 8 groups of 32 lanes
    const int d0  = blockIdx.x * 32;

    float sa = 0.f, la = 0.f;
    for (int b = g; b < SBLK; b += 8) {
        float sc = __expf(ws_m[b] - M);
        sa += sacc[b*DDIM + d0 + ell] * sc;
        la += lacc[b*DDIM + d0 + ell];
    }
    r1[t] = sa; r2[t] = la;
    __syncthreads();
    if (g == 0) {
        float S = 0.f, Q = 0.f;
        #pragma unroll
        for (int gg = 0; gg < 8; gg++) { S += r1[gg*32 + ell]; Q += r2[gg*32 + ell]; }
        fused[DDIM   + d0 + ell] = S / L;   // r_s
        fused[2*DDIM + d0 + ell] = Q;       // r_l
    }

    if (blockIdx.x == 0) {
        fused[t] = x_t[t];                  // x part of fused
        hbuf[t]        = b1[t];             // init h with bias (atomics add later)
        hbuf[t + 256]  = b1[t + 256];
        out[t]         = b2[t];             // init out with bias
    }
}

// ---------------------------------------------------------------------------
// Kernel C: h += fused @ w1 over a k-chunk of 64. grid = 12 kchunks x 2 halves.
// ---------------------------------------------------------------------------
__global__ __launch_bounds__(256) void kC(const float* __restrict__ w1,
                                          float* __restrict__ ws)
{
    __shared__ float fl[64];
    const int t     = threadIdx.x;
    const int k0    = (blockIdx.x >> 1) * 64;
    const int h_idx = (blockIdx.x & 1) * 256 + t;
    const float* fused = ws + OFF_FUSED;
    float* hbuf = ws + OFF_H;

    if (t < 64) fl[t] = fused[k0 + t];
    __syncthreads();

    float acc = 0.f;
    #pragma unroll 8
    for (int k = 0; k < 64; k++)
        acc += fl[k] * w1[(k0 + k) * HID + h_idx];   // coalesced over h_idx
    atomicAdd(&hbuf[h_idx], acc);
}

// ---------------------------------------------------------------------------
// Kernel D: out += relu(h) @ w2 over a k-chunk of 64. grid = 8 kchunks.
// ---------------------------------------------------------------------------
__global__ __launch_bounds__(256) void kD(const float* __restrict__ w2,
                                          const float* __restrict__ ws,
                                          float* __restrict__ out)
{
    __shared__ float hl[64];
    const int t  = threadIdx.x;
    const int k0 = blockIdx.x * 64;
    const float* hbuf = ws + OFF_H;

    if (t < 64) hl[t] = fmaxf(hbuf[k0 + t], 0.f);
    __syncthreads();

    float acc = 0.f;
    #pragma unroll 8
    for (int k = 0; k < 64; k++)
        acc += hl[k] * w2[(k0 + k) * DDIM + t];      // coalesced over t
    atomicAdd(&out[t], acc);
}

extern "C" void kernel_launch(void* const* d_in, const int* in_sizes, int n_in,
                              void* d_out, int out_size, void* d_ws, size_t ws_size,
                              hipStream_t stream)
{
    const float* x_t     = (const float*)d_in[0];
    const float* stm_emb = (const float*)d_in[1];
    const float* stm_w   = (const float*)d_in[2];
    const float* ltm_emb = (const float*)d_in[3];
    const float* ltm_w   = (const float*)d_in[4];
    const float* w1      = (const float*)d_in[5];
    const float* b1      = (const float*)d_in[6];
    const float* w2      = (const float*)d_in[7];
    const float* b2      = (const float*)d_in[8];
    float* out = (float*)d_out;
    float* ws  = (float*)d_ws;
    const int N = in_sizes[2];   // 100000

    kA<<<2 * SBLK, 256, 0, stream>>>(x_t, stm_emb, stm_w, ltm_emb, ltm_w, ws, N);
    kB<<<8,        256, 0, stream>>>(x_t, b1, b2, ws, out);
    kC<<<24,       256, 0, stream>>>(w1, ws);
    kD<<<8,        256, 0, stream>>>(w2, ws, out);
}

// Round 2
// 254.580 us; speedup vs baseline: 1.0791x; 1.0791x over previous
//
#include <hip/hip_runtime.h>
#include <math.h>

// Problem constants (match reference: D=256, HID=512, N=100000)
#define DDIM   256
#define HID    512
#define SBLK   512   // number of stm partial blocks (also ltm)

// Workspace layout (float offsets)
#define OFF_M     0
#define OFF_L     (SBLK)
#define OFF_SACC  (2*SBLK)
#define OFF_LACC  (OFF_SACC + SBLK*DDIM)
#define OFF_FUSED (OFF_LACC + SBLK*DDIM)
#define OFF_H     (OFF_FUSED + 3*DDIM)
// total floats = 2*512 + 2*512*256 + 768 + 512 = 264448  (~1.01 MB)

// ---------------------------------------------------------------------------
// Kernel A: the heavy pass. blocks [0,512): stm online-softmax partials.
//           blocks [512,1024): ltm weighted-sum partials.
// Branch-free online softmax, 4 rows (one contiguous quad) per iteration per
// wave so 4+ independent global loads are in flight and the carried
// (m,l,acc) rescale happens once per 4 rows.
// ---------------------------------------------------------------------------
__global__ __launch_bounds__(256) void kA(const float* __restrict__ x_t,
                                          const float* __restrict__ stm_emb,
                                          const float* __restrict__ stm_w,
                                          const float* __restrict__ ltm_emb,
                                          const float* __restrict__ ltm_w,
                                          float* __restrict__ ws, int N)
{
    const int t    = threadIdx.x;
    const int lane = t & 63;
    const int wave = t >> 6;

    __shared__ float s_acc[4][DDIM];
    __shared__ float s_m[4];
    __shared__ float s_l[4];

    const float4 x4 = reinterpret_cast<const float4*>(x_t)[lane];

    const int bid = blockIdx.x;
    if (bid < SBLK) {
        // ---- STM: online softmax + weighted-sum fused, one pass ----
        const int b  = bid;
        const int rs = (int)(((long long)b     * N) / SBLK);
        const int re = (int)(((long long)(b+1) * N) / SBLK);
        const int T  = re - rs;
        const int nq = T >> 2;                     // full quads of 4 rows
        const float4* emb4 = reinterpret_cast<const float4*>(stm_emb);

        float m = -1e30f, l = 0.f;
        float ax = 0.f, ay = 0.f, az = 0.f, aw = 0.f;

        for (int qi = wave; qi < nq; qi += 4) {
            const int r = rs + (qi << 2);
            float4 e0 = emb4[(size_t)(r+0) * 64 + lane];
            float4 e1 = emb4[(size_t)(r+1) * 64 + lane];
            float4 e2 = emb4[(size_t)(r+2) * 64 + lane];
            float4 e3 = emb4[(size_t)(r+3) * 64 + lane];
            float w0 = stm_w[r+0], w1v = stm_w[r+1];
            float w2v = stm_w[r+2], w3v = stm_w[r+3];

            float p0 = e0.x*x4.x + e0.y*x4.y + e0.z*x4.z + e0.w*x4.w;
            float p1 = e1.x*x4.x + e1.y*x4.y + e1.z*x4.z + e1.w*x4.w;
            float p2 = e2.x*x4.x + e2.y*x4.y + e2.z*x4.z + e2.w*x4.w;
            float p3 = e3.x*x4.x + e3.y*x4.y + e3.z*x4.z + e3.w*x4.w;
            #pragma unroll
            for (int off = 32; off > 0; off >>= 1) {   // 4 independent chains
                p0 += __shfl_xor(p0, off, 64);
                p1 += __shfl_xor(p1, off, 64);
                p2 += __shfl_xor(p2, off, 64);
                p3 += __shfl_xor(p3, off, 64);
            }
            float s0 = p0 * w0, s1 = p1 * w1v, s2 = p2 * w2v, s3 = p3 * w3v;

            float smax = fmaxf(fmaxf(s0, s1), fmaxf(s2, s3));
            float mn   = fmaxf(m, smax);
            float sc   = __expf(m - mn);           // first iter: exp(-huge)=0
            float q0 = __expf(s0 - mn), q1 = __expf(s1 - mn);
            float q2 = __expf(s2 - mn), q3 = __expf(s3 - mn);
            m = mn;
            l  = l*sc + ((q0 + q1) + (q2 + q3));
            ax = ax*sc + (q0*e0.x + q1*e1.x) + (q2*e2.x + q3*e3.x);
            ay = ay*sc + (q0*e0.y + q1*e1.y) + (q2*e2.y + q3*e3.y);
            az = az*sc + (q0*e0.z + q1*e1.z) + (q2*e2.z + q3*e3.z);
            aw = aw*sc + (q0*e0.w + q1*e1.w) + (q2*e2.w + q3*e3.w);
        }
        // tail rows (T & 3 of them), one per wave, branch-free body
        {
            const int r = rs + (nq << 2) + wave;
            if (r < re) {
                float4 e = emb4[(size_t)r * 64 + lane];
                float wv = stm_w[r];
                float p = e.x*x4.x + e.y*x4.y + e.z*x4.z + e.w*x4.w;
                #pragma unroll
                for (int off = 32; off > 0; off >>= 1)
                    p += __shfl_xor(p, off, 64);
                float s  = p * wv;
                float mn = fmaxf(m, s);
                float sc = __expf(m - mn);
                float q  = __expf(s - mn);
                m = mn;
                l  = l*sc + q;
                ax = ax*sc + q*e.x; ay = ay*sc + q*e.y;
                az = az*sc + q*e.z; aw = aw*sc + q*e.w;
            }
        }

        s_acc[wave][lane*4+0] = ax;
        s_acc[wave][lane*4+1] = ay;
        s_acc[wave][lane*4+2] = az;
        s_acc[wave][lane*4+3] = aw;
        if (lane == 0) { s_m[wave] = m; s_l[wave] = l; }
        __syncthreads();

        // block-level softmax merge (every wave has >=48 rows, all m finite)
        float M  = fmaxf(fmaxf(s_m[0], s_m[1]), fmaxf(s_m[2], s_m[3]));
        float e0 = __expf(s_m[0] - M), e1 = __expf(s_m[1] - M);
        float e2 = __expf(s_m[2] - M), e3 = __expf(s_m[3] - M);
        float L  = s_l[0]*e0 + s_l[1]*e1 + s_l[2]*e2 + s_l[3]*e3;
        float av = s_acc[0][t]*e0 + s_acc[1][t]*e1 + s_acc[2][t]*e2 + s_acc[3][t]*e3;
        ws[OFF_SACC + b*DDIM + t] = av;
        if (t == 0) { ws[OFF_M + b] = M; ws[OFF_L + b] = L; }
    } else {
        // ---- LTM: plain weighted sum, quad-unrolled ----
        const int b  = bid - SBLK;
        const int rs = (int)(((long long)b     * N) / SBLK);
        const int re = (int)(((long long)(b+1) * N) / SBLK);
        const int T  = re - rs;
        const int nq = T >> 2;
        const float4* emb4 = reinterpret_cast<const float4*>(ltm_emb);

        float ax = 0.f, ay = 0.f, az = 0.f, aw = 0.f;
        for (int qi = wave; qi < nq; qi += 4) {
            const int r = rs + (qi << 2);
            float4 e0 = emb4[(size_t)(r+0) * 64 + lane];
            float4 e1 = emb4[(size_t)(r+1) * 64 + lane];
            float4 e2 = emb4[(size_t)(r+2) * 64 + lane];
            float4 e3 = emb4[(size_t)(r+3) * 64 + lane];
            float w0 = ltm_w[r+0], w1v = ltm_w[r+1];
            float w2v = ltm_w[r+2], w3v = ltm_w[r+3];
            ax += (w0*e0.x + w1v*e1.x) + (w2v*e2.x + w3v*e3.x);
            ay += (w0*e0.y + w1v*e1.y) + (w2v*e2.y + w3v*e3.y);
            az += (w0*e0.z + w1v*e1.z) + (w2v*e2.z + w3v*e3.z);
            aw += (w0*e0.w + w1v*e1.w) + (w2v*e2.w + w3v*e3.w);
        }
        {
            const int r = rs + (nq << 2) + wave;
            if (r < re) {
                float4 e = emb4[(size_t)r * 64 + lane];
                float wv = ltm_w[r];
                ax += wv*e.x; ay += wv*e.y; az += wv*e.z; aw += wv*e.w;
            }
        }
        s_acc[wave][lane*4+0] = ax;
        s_acc[wave][lane*4+1] = ay;
        s_acc[wave][lane*4+2] = az;
        s_acc[wave][lane*4+3] = aw;
        __syncthreads();
        float av = s_acc[0][t] + s_acc[1][t] + s_acc[2][t] + s_acc[3][t];
        ws[OFF_LACC + b*DDIM + t] = av;
    }
}

// ---------------------------------------------------------------------------
// Kernel B: merge the 512 softmax partials + 512 ltm partials -> fused[768].
// grid=8 blocks; each block redundantly computes global (M,L) and an LDS
// table of per-block scales sc[b]=exp(m_b-M), then owns 32 d-columns.
// Block 0 also copies x_t into fused, inits h=b1 and out=b2.
// ---------------------------------------------------------------------------
__global__ __launch_bounds__(256) void kB(const float* __restrict__ x_t,
                                          const float* __restrict__ b1,
                                          const float* __restrict__ b2,
                                          float* __restrict__ ws,
                                          float* __restrict__ out)
{
    __shared__ float red[256];
    __shared__ float scl[SBLK];
    __shared__ float r1[256];
    __shared__ float r2[256];
    const int t = threadIdx.x;

    const float* ws_m = ws + OFF_M;
    const float* ws_l = ws + OFF_L;
    const float* sacc = ws + OFF_SACC;
    const float* lacc = ws + OFF_LACC;
    float* fused = ws + OFF_FUSED;
    float* hbuf  = ws + OFF_H;

    // global max M over 512 block maxima
    float m0 = ws_m[t], m1 = ws_m[t + 256];
    red[t] = fmaxf(m0, m1); __syncthreads();
    for (int s = 128; s > 0; s >>= 1) {
        if (t < s) red[t] = fmaxf(red[t], red[t + s]);
        __syncthreads();
    }
    const float M = red[0];
    __syncthreads();

    // per-partial scales into LDS, then global denominator L
    float sc0 = __expf(m0 - M), sc1 = __expf(m1 - M);
    scl[t] = sc0; scl[t + 256] = sc1;
    red[t] = ws_l[t] * sc0 + ws_l[t + 256] * sc1;
    __syncthreads();
    for (int s = 128; s > 0; s >>= 1) {
        if (t < s) red[t] += red[t + s];
        __syncthreads();
    }
    const float L = red[0];
    __syncthreads();

    // this block owns d in [d0, d0+32)
    const int ell = t & 31;
    const int g   = t >> 5;          // 8 groups of 32 lanes
    const int d0  = blockIdx.x * 32;

    float sa = 0.f, la = 0.f;
    #pragma unroll 4
    for (int b = g; b < SBLK; b += 8) {
        sa += sacc[b*DDIM + d0 + ell] * scl[b];
        la += lacc[b*DDIM + d0 + ell];
    }
    r1[t] = sa; r2[t] = la;
    __syncthreads();
    if (g == 0) {
        float S = 0.f, Q = 0.f;
        #pragma unroll
        for (int gg = 0; gg < 8; gg++) { S += r1[gg*32 + ell]; Q += r2[gg*32 + ell]; }
        fused[DDIM   + d0 + ell] = S / L;   // r_s
        fused[2*DDIM + d0 + ell] = Q;       // r_l
    }

    if (blockIdx.x == 0) {
        fused[t] = x_t[t];                  // x part of fused
        hbuf[t]        = b1[t];             // init h with bias (atomics add later)
        hbuf[t + 256]  = b1[t + 256];
        out[t]         = b2[t];             // init out with bias
    }
}

// ---------------------------------------------------------------------------
// Kernel C: h += fused @ w1 over a k-chunk of 64. grid = 12 kchunks x 2 halves.
// ---------------------------------------------------------------------------
__global__ __launch_bounds__(256) void kC(const float* __restrict__ w1,
                                          float* __restrict__ ws)
{
    __shared__ float fl[64];
    const int t     = threadIdx.x;
    const int k0    = (blockIdx.x >> 1) * 64;
    const int h_idx = (blockIdx.x & 1) * 256 + t;
    const float* fused = ws + OFF_FUSED;
    float* hbuf = ws + OFF_H;

    if (t < 64) fl[t] = fused[k0 + t];
    __syncthreads();

    float acc = 0.f;
    #pragma unroll 16
    for (int k = 0; k < 64; k++)
        acc += fl[k] * w1[(k0 + k) * HID + h_idx];   // coalesced over h_idx
    atomicAdd(&hbuf[h_idx], acc);
}

// ---------------------------------------------------------------------------
// Kernel D: out += relu(h) @ w2 over a k-chunk of 64. grid = 8 kchunks.
// ---------------------------------------------------------------------------
__global__ __launch_bounds__(256) void kD(const float* __restrict__ w2,
                                          const float* __restrict__ ws,
                                          float* __restrict__ out)
{
    __shared__ float hl[64];
    const int t  = threadIdx.x;
    const int k0 = blockIdx.x * 64;
    const float* hbuf = ws + OFF_H;

    if (t < 64) hl[t] = fmaxf(hbuf[k0 + t], 0.f);
    __syncthreads();

    float acc = 0.f;
    #pragma unroll 16
    for (int k = 0; k < 64; k++)
        acc += hl[k] * w2[(k0 + k) * DDIM + t];      // coalesced over t
    atomicAdd(&out[t], acc);
}

extern "C" void kernel_launch(void* const* d_in, const int* in_sizes, int n_in,
                              void* d_out, int out_size, void* d_ws, size_t ws_size,
                              hipStream_t stream)
{
    const float* x_t     = (const float*)d_in[0];
    const float* stm_emb = (const float*)d_in[1];
    const float* stm_w   = (const float*)d_in[2];
    const float* ltm_emb = (const float*)d_in[3];
    const float* ltm_w   = (const float*)d_in[4];
    const float* w1      = (const float*)d_in[5];
    const float* b1      = (const float*)d_in[6];
    const float* w2      = (const float*)d_in[7];
    const float* b2      = (const float*)d_in[8];
    float* out = (float*)d_out;
    float* ws  = (float*)d_ws;
    const int N = in_sizes[2];   // 100000

    kA<<<2 * SBLK, 256, 0, stream>>>(x_t, stm_emb, stm_w, ltm_emb, ltm_w, ws, N);
    kB<<<8,        256, 0, stream>>>(x_t, b1, b2, ws, out);
    kC<<<24,       256, 0, stream>>>(w1, ws);
    kD<<<8,        256, 0, stream>>>(w2, ws, out);
}

// Round 3
// 253.804 us; speedup vs baseline: 1.0824x; 1.0031x over previous
//
#include <hip/hip_runtime.h>
#include <math.h>

// Problem constants (match reference: D=256, HID=512, N=100000)
#define DDIM   256
#define HID    512
#define SBLK   512   // number of stm partial blocks (also ltm)

// Workspace layout (float offsets)
#define OFF_M     0
#define OFF_L     (SBLK)
#define OFF_SACC  (2*SBLK)
#define OFF_LACC  (OFF_SACC + SBLK*DDIM)
#define OFF_FUSED (OFF_LACC + SBLK*DDIM)
#define OFF_H     (OFF_FUSED + 3*DDIM)
// total floats = 2*512 + 2*512*256 + 768 + 512 = 264448  (~1.01 MB)

// ---------------------------------------------------------------------------
// Kernel A: blocks [0,512): stm online-softmax partials; [512,1024): ltm sums.
// 512 threads = 8 waves/block -> 32 waves/CU. Each wave owns whole row-quads
// (4 consecutive rows, 4KB contiguous); lanes split D=256 as float4.
// Explicit 1-deep software pipeline: next quad's 4 embedding float4s + weight
// float4 are issued BEFORE the current quad's reduce/exp/accumulate chain, so
// ~4 global loads per wave stay in flight continuously.
// ---------------------------------------------------------------------------
__global__ __launch_bounds__(512, 8) void kA(const float* __restrict__ x_t,
                                             const float* __restrict__ stm_emb,
                                             const float* __restrict__ stm_w,
                                             const float* __restrict__ ltm_emb,
                                             const float* __restrict__ ltm_w,
                                             float* __restrict__ ws, int N)
{
    const int t    = threadIdx.x;
    const int lane = t & 63;
    const int wave = t >> 6;          // 8 waves

    __shared__ float s_acc[8][DDIM];  // 8 KB
    __shared__ float s_m[8];
    __shared__ float s_l[8];

    const float4 x4 = reinterpret_cast<const float4*>(x_t)[lane];
    const int Q   = N >> 2;           // full row-quads (N=100000 -> 25000, tail N&3)
    const int bid = blockIdx.x;

    if (bid < SBLK) {
        // ---- STM: fused online-softmax + weighted accumulate ----
        const int b  = bid;
        const int qs = (int)(((long long)b     * Q) / SBLK);
        const int qe = (int)(((long long)(b+1) * Q) / SBLK);
        const float4* emb4 = reinterpret_cast<const float4*>(stm_emb);
        const float4* w4   = reinterpret_cast<const float4*>(stm_w);

        float m = -1e30f, l = 0.f;
        float ax = 0.f, ay = 0.f, az = 0.f, aw = 0.f;

        int q = qs + wave;
        if (q < qe) {
            size_t base = (size_t)q * 256 + lane;       // float4 index of row 4q
            float4 E0 = emb4[base      ];
            float4 E1 = emb4[base +  64];
            float4 E2 = emb4[base + 128];
            float4 E3 = emb4[base + 192];
            float4 W  = w4[q];
            while (true) {
                const int  qn   = q + 8;
                const bool more = qn < qe;
                const int  qp   = more ? qn : q;        // clamp: harmless L1-hit reload
                size_t pb = (size_t)qp * 256 + lane;
                float4 F0 = emb4[pb      ];             // prefetch issued FIRST
                float4 F1 = emb4[pb +  64];
                float4 F2 = emb4[pb + 128];
                float4 F3 = emb4[pb + 192];
                float4 Wn = w4[qp];

                float p0 = E0.x*x4.x + E0.y*x4.y + E0.z*x4.z + E0.w*x4.w;
                float p1 = E1.x*x4.x + E1.y*x4.y + E1.z*x4.z + E1.w*x4.w;
                float p2 = E2.x*x4.x + E2.y*x4.y + E2.z*x4.z + E2.w*x4.w;
                float p3 = E3.x*x4.x + E3.y*x4.y + E3.z*x4.z + E3.w*x4.w;
                #pragma unroll
                for (int off = 32; off > 0; off >>= 1) { // 4 independent chains
                    p0 += __shfl_xor(p0, off, 64);
                    p1 += __shfl_xor(p1, off, 64);
                    p2 += __shfl_xor(p2, off, 64);
                    p3 += __shfl_xor(p3, off, 64);
                }
                float s0 = p0 * W.x, s1 = p1 * W.y;
                float s2 = p2 * W.z, s3 = p3 * W.w;

                float smax = fmaxf(fmaxf(s0, s1), fmaxf(s2, s3));
                float mn   = fmaxf(m, smax);
                float sc   = __expf(m - mn);
                float q0 = __expf(s0 - mn), q1 = __expf(s1 - mn);
                float q2 = __expf(s2 - mn), q3 = __expf(s3 - mn);
                m = mn;
                l  = l*sc + ((q0 + q1) + (q2 + q3));
                ax = ax*sc + (q0*E0.x + q1*E1.x) + (q2*E2.x + q3*E3.x);
                ay = ay*sc + (q0*E0.y + q1*E1.y) + (q2*E2.y + q3*E3.y);
                az = az*sc + (q0*E0.z + q1*E1.z) + (q2*E2.z + q3*E3.z);
                aw = aw*sc + (q0*E0.w + q1*E1.w) + (q2*E2.w + q3*E3.w);

                if (!more) break;
                E0 = F0; E1 = F1; E2 = F2; E3 = F3; W = Wn; q = qn;
            }
        }
        // tail rows (N & 3, zero for N=100000) handled by last stm block
        if (b == SBLK - 1) {
            const int tail = N & 3;
            const int r    = (Q << 2) + wave;
            if (wave < tail) {
                float4 e = reinterpret_cast<const float4*>(stm_emb)[(size_t)r * 64 + lane];
                float wv = stm_w[r];
                float p = e.x*x4.x + e.y*x4.y + e.z*x4.z + e.w*x4.w;
                #pragma unroll
                for (int off = 32; off > 0; off >>= 1)
                    p += __shfl_xor(p, off, 64);
                float s  = p * wv;
                float mn = fmaxf(m, s);
                float sc = __expf(m - mn);
                float qq = __expf(s - mn);
                m = mn;
                l  = l*sc + qq;
                ax = ax*sc + qq*e.x; ay = ay*sc + qq*e.y;
                az = az*sc + qq*e.z; aw = aw*sc + qq*e.w;
            }
        }

        reinterpret_cast<float4*>(s_acc[wave])[lane] = make_float4(ax, ay, az, aw);
        if (lane == 0) { s_m[wave] = m; s_l[wave] = l; }
        __syncthreads();

        if (t < DDIM) {
            float M = s_m[0];
            #pragma unroll
            for (int w = 1; w < 8; w++) M = fmaxf(M, s_m[w]);
            float L = 0.f, av = 0.f;
            #pragma unroll
            for (int w = 0; w < 8; w++) {
                float e = __expf(s_m[w] - M);
                L  += s_l[w] * e;
                av += s_acc[w][t] * e;
            }
            ws[OFF_SACC + b*DDIM + t] = av;
            if (t == 0) { ws[OFF_M + b] = M; ws[OFF_L + b] = L; }
        }
    } else {
        // ---- LTM: plain weighted sum, same pipelined stream ----
        const int b  = bid - SBLK;
        const int qs = (int)(((long long)b     * Q) / SBLK);
        const int qe = (int)(((long long)(b+1) * Q) / SBLK);
        const float4* emb4 = reinterpret_cast<const float4*>(ltm_emb);
        const float4* w4   = reinterpret_cast<const float4*>(ltm_w);

        float ax = 0.f, ay = 0.f, az = 0.f, aw = 0.f;
        int q = qs + wave;
        if (q < qe) {
            size_t base = (size_t)q * 256 + lane;
            float4 E0 = emb4[base      ];
            float4 E1 = emb4[base +  64];
            float4 E2 = emb4[base + 128];
            float4 E3 = emb4[base + 192];
            float4 W  = w4[q];
            while (true) {
                const int  qn   = q + 8;
                const bool more = qn < qe;
                const int  qp   = more ? qn : q;
                size_t pb = (size_t)qp * 256 + lane;
                float4 F0 = emb4[pb      ];
                float4 F1 = emb4[pb +  64];
                float4 F2 = emb4[pb + 128];
                float4 F3 = emb4[pb + 192];
                float4 Wn = w4[qp];

                ax += (W.x*E0.x + W.y*E1.x) + (W.z*E2.x + W.w*E3.x);
                ay += (W.x*E0.y + W.y*E1.y) + (W.z*E2.y + W.w*E3.y);
                az += (W.x*E0.z + W.y*E1.z) + (W.z*E2.z + W.w*E3.z);
                aw += (W.x*E0.w + W.y*E1.w) + (W.z*E2.w + W.w*E3.w);

                if (!more) break;
                E0 = F0; E1 = F1; E2 = F2; E3 = F3; W = Wn; q = qn;
            }
        }
        if (b == SBLK - 1) {
            const int tail = N & 3;
            const int r    = (Q << 2) + wave;
            if (wave < tail) {
                float4 e = reinterpret_cast<const float4*>(ltm_emb)[(size_t)r * 64 + lane];
                float wv = ltm_w[r];
                ax += wv*e.x; ay += wv*e.y; az += wv*e.z; aw += wv*e.w;
            }
        }

        reinterpret_cast<float4*>(s_acc[wave])[lane] = make_float4(ax, ay, az, aw);
        __syncthreads();
        if (t < DDIM) {
            float av = 0.f;
            #pragma unroll
            for (int w = 0; w < 8; w++) av += s_acc[w][t];
            ws[OFF_LACC + b*DDIM + t] = av;
        }
    }
}

// ---------------------------------------------------------------------------
// Kernel B: merge the 512 softmax partials + 512 ltm partials -> fused[768].
// grid=8 blocks; each block redundantly computes global (M,L) and an LDS
// table of per-block scales sc[b]=exp(m_b-M), then owns 32 d-columns.
// Block 0 also copies x_t into fused, inits h=b1 and out=b2.
// ---------------------------------------------------------------------------
__global__ __launch_bounds__(256) void kB(const float* __restrict__ x_t,
                                          const float* __restrict__ b1,
                                          const float* __restrict__ b2,
                                          float* __restrict__ ws,
                                          float* __restrict__ out)
{
    __shared__ float red[256];
    __shared__ float scl[SBLK];
    __shared__ float r1[256];
    __shared__ float r2[256];
    const int t = threadIdx.x;

    const float* ws_m = ws + OFF_M;
    const float* ws_l = ws + OFF_L;
    const float* sacc = ws + OFF_SACC;
    const float* lacc = ws + OFF_LACC;
    float* fused = ws + OFF_FUSED;
    float* hbuf  = ws + OFF_H;

    // global max M over 512 block maxima
    float m0 = ws_m[t], m1 = ws_m[t + 256];
    red[t] = fmaxf(m0, m1); __syncthreads();
    for (int s = 128; s > 0; s >>= 1) {
        if (t < s) red[t] = fmaxf(red[t], red[t + s]);
        __syncthreads();
    }
    const float M = red[0];
    __syncthreads();

    // per-partial scales into LDS, then global denominator L
    float sc0 = __expf(m0 - M), sc1 = __expf(m1 - M);
    scl[t] = sc0; scl[t + 256] = sc1;
    red[t] = ws_l[t] * sc0 + ws_l[t + 256] * sc1;
    __syncthreads();
    for (int s = 128; s > 0; s >>= 1) {
        if (t < s) red[t] += red[t + s];
        __syncthreads();
    }
    const float L = red[0];
    __syncthreads();

    // this block owns d in [d0, d0+32)
    const int ell = t & 31;
    const int g   = t >> 5;          // 8 groups of 32 lanes
    const int d0  = blockIdx.x * 32;

    float sa = 0.f, la = 0.f;
    #pragma unroll 4
    for (int b = g; b < SBLK; b += 8) {
        sa += sacc[b*DDIM + d0 + ell] * scl[b];
        la += lacc[b*DDIM + d0 + ell];
    }
    r1[t] = sa; r2[t] = la;
    __syncthreads();
    if (g == 0) {
        float S = 0.f, Qs = 0.f;
        #pragma unroll
        for (int gg = 0; gg < 8; gg++) { S += r1[gg*32 + ell]; Qs += r2[gg*32 + ell]; }
        fused[DDIM   + d0 + ell] = S / L;   // r_s
        fused[2*DDIM + d0 + ell] = Qs;      // r_l
    }

    if (blockIdx.x == 0) {
        fused[t] = x_t[t];                  // x part of fused
        hbuf[t]        = b1[t];             // init h with bias (atomics add later)
        hbuf[t + 256]  = b1[t + 256];
        out[t]         = b2[t];             // init out with bias
    }
}

// ---------------------------------------------------------------------------
// Kernel C: h += fused @ w1 over a k-chunk of 64. grid = 12 kchunks x 2 halves.
// ---------------------------------------------------------------------------
__global__ __launch_bounds__(256) void kC(const float* __restrict__ w1,
                                          float* __restrict__ ws)
{
    __shared__ float fl[64];
    const int t     = threadIdx.x;
    const int k0    = (blockIdx.x >> 1) * 64;
    const int h_idx = (blockIdx.x & 1) * 256 + t;
    const float* fused = ws + OFF_FUSED;
    float* hbuf = ws + OFF_H;

    if (t < 64) fl[t] = fused[k0 + t];
    __syncthreads();

    float acc = 0.f;
    #pragma unroll 16
    for (int k = 0; k < 64; k++)
        acc += fl[k] * w1[(k0 + k) * HID + h_idx];   // coalesced over h_idx
    atomicAdd(&hbuf[h_idx], acc);
}

// ---------------------------------------------------------------------------
// Kernel D: out += relu(h) @ w2 over a k-chunk of 64. grid = 8 kchunks.
// ---------------------------------------------------------------------------
__global__ __launch_bounds__(256) void kD(const float* __restrict__ w2,
                                          const float* __restrict__ ws,
                                          float* __restrict__ out)
{
    __shared__ float hl[64];
    const int t  = threadIdx.x;
    const int k0 = blockIdx.x * 64;
    const float* hbuf = ws + OFF_H;

    if (t < 64) hl[t] = fmaxf(hbuf[k0 + t], 0.f);
    __syncthreads();

    float acc = 0.f;
    #pragma unroll 16
    for (int k = 0; k < 64; k++)
        acc += hl[k] * w2[(k0 + k) * DDIM + t];      // coalesced over t
    atomicAdd(&out[t], acc);
}

extern "C" void kernel_launch(void* const* d_in, const int* in_sizes, int n_in,
                              void* d_out, int out_size, void* d_ws, size_t ws_size,
                              hipStream_t stream)
{
    const float* x_t     = (const float*)d_in[0];
    const float* stm_emb = (const float*)d_in[1];
    const float* stm_w   = (const float*)d_in[2];
    const float* ltm_emb = (const float*)d_in[3];
    const float* ltm_w   = (const float*)d_in[4];
    const float* w1      = (const float*)d_in[5];
    const float* b1      = (const float*)d_in[6];
    const float* w2      = (const float*)d_in[7];
    const float* b2      = (const float*)d_in[8];
    float* out = (float*)d_out;
    float* ws  = (float*)d_ws;
    const int N = in_sizes[2];   // 100000

    kA<<<2 * SBLK, 512, 0, stream>>>(x_t, stm_emb, stm_w, ltm_emb, ltm_w, ws, N);
    kB<<<8,        256, 0, stream>>>(x_t, b1, b2, ws, out);
    kC<<<24,       256, 0, stream>>>(w1, ws);
    kD<<<8,        256, 0, stream>>>(w2, ws, out);
}